// Round 9
// baseline (94.198 us; speedup 1.0000x reference)
//
#include <hip/hip_runtime.h>

#define T      64
#define S      32
#define NGRAPH 64
#define NSPLIT 16     // slices per graph -> 1024 blocks of 256
#define NW     4

// Delta-encoded ECT, 2-exact-slot version. Per (node,theta) the sigmoid
// profile over s is 0..0, sm, s0, ~1..1. First difference: 3 nonzero deltas
// at slots ss-1, ss, ss+1 (third approximated as 1-s0; true sigma there is
// >= 1-8.2e-4). Slots <=0 fold into a per-thread base register (profile value
// at s=0); slots >=32 go to a trash bin. Partial stores RAW merged bins
// (base + deltas 1..31) -> prefix-sum deferred to the reduce kernel.
__global__ __launch_bounds__(256, 4) void ect_partial(
    const float* __restrict__ x, const float* __restrict__ v,
    const float* __restrict__ lin, const int* __restrict__ batch,
    float* __restrict__ ws, int n_points)
{
    __shared__ float bins[256 * 34];  // [tid][c]: 0=base(v0acc), 1..31 deltas, 33 trash

    const int tid  = threadIdx.x;
    const int t    = tid & 63;        // lane == theta
    const int w    = tid >> 6;        // wave id
    const int b    = blockIdx.x;
    const int g    = b >> 4;          // graph
    const int c    = b & (NSPLIT - 1);

    for (int i = tid; i < 256 * 34; i += 256) bins[i] = 0.0f;

    // 32-ary ballot search (lanes<32: lower_bound(g), >=32: lower_bound(g+1))
    const int target = (t < 32) ? g : (g + 1);
    const int i32    = t & 31;
    int lo = 0;
    const int strides[3] = {2048, 64, 2};
#pragma unroll
    for (int rnd = 0; rnd < 3; rnd++) {
        const int stride = strides[rnd];
        const int idx  = lo + i32 * stride;
        const int pv   = batch[min(idx, n_points - 1)];
        const bool prd = (idx < n_points) && (pv < target);
        const unsigned long long bal = __ballot(prd);
        const int cnt = __popc((unsigned)(bal >> (t & 32)));
        lo += max(cnt - 1, 0) * stride;
    }
#pragma unroll
    for (int rnd = 0; rnd < 2; rnd++) {         // final range of 2
        const int idx = min(lo, n_points - 1);
        if ((lo < n_points) && (batch[idx] < target)) lo++;
    }
    const int gstart = __builtin_amdgcn_readfirstlane(lo);   // lane 0
    const int gend   = __builtin_amdgcn_readlane(lo, 32);    // lane 32
    const int len    = gend - gstart;
    const int n0     = gstart + (len * c) / NSPLIT;
    const int n1     = gstart + (len * (c + 1)) / NSPLIT;

    const float lin0     = lin[0];
    const float step     = lin[1] - lin0;
    const float inv_step = 1.0f / step;
    const float nl0i     = -lin0 * inv_step;
    const float K2 = (100.0f * step) * 1.4426950408889634f;   // ~10.24
    const float r  = __builtin_amdgcn_exp2f(-K2);

    const float v0 = v[0 * T + t];
    const float v1 = v[1 * T + t];
    const float v2 = v[2 * T + t];

    float v0acc = 0.0f;                 // profile value at s=0, accumulated
    const int binb = tid * 34;

#pragma unroll 2
    for (int n = n0 + w; n < n1; n += NW) {     // n is wave-uniform (SGPR)
        const float x0 = x[3 * n + 0];          // scalar loads (uniform addr)
        const float x1 = x[3 * n + 1];
        const float x2 = x[3 * n + 2];
        const float nh = fmaf(x0, v0, fmaf(x1, v1, x2 * v2));
        const float f  = fmaf(nh, inv_step, nl0i);
        const float fs = ceilf(f);
        const int   ss = (int)fs;
        const float e0 = __builtin_amdgcn_exp2f(fmaf(K2, f - fs, K2)); // (1,e^d]
        const float e1 = e0 * r;                                        // (r,1]
        const float sm  = __builtin_amdgcn_rcpf(1.0f + e0);
        const float s0v = __builtin_amdgcn_rcpf(1.0f + e1);
        // base: profile(0) = 0 (ss>=2), sm (ss==1), s0 (ss==0), ~1 (ss<=-1)
        v0acc += (ss <= -1) ? 1.0f : (ss == 0 ? s0v : (ss == 1 ? sm : 0.0f));
        // deltas at slots ss-1, ss, ss+1; in-range [1,31] else trash (33)
        const int p0 = ss - 1, p1 = ss, p2 = ss + 1;
        const int a0 = binb + (((unsigned)(p0 - 1) < 31u) ? p0 : 33);
        const int a1 = binb + (((unsigned)(p1 - 1) < 31u) ? p1 : 33);
        const int a2 = binb + (((unsigned)(p2 - 1) < 31u) ? p2 : 33);
        bins[a0] += sm;
        bins[a1] += s0v - sm;
        bins[a2] += 1.0f - s0v;
    }

    bins[binb + 0] = v0acc;
    __syncthreads();

    // merge 4 wave-banks and store RAW bins (c=0 base, 1..31 deltas, 32 unused->0)
    float* wsb = ws + (size_t)b * (33 * 64);
    for (int cell = tid; cell < 33 * 64; cell += 256) {
        const int cc = cell >> 6;               // 0..32
        const int tt = cell & 63;
        const float sum = bins[(  0 + tt) * 34 + cc] + bins[( 64 + tt) * 34 + cc]
                        + bins[(128 + tt) * 34 + cc] + bins[(192 + tt) * 34 + cc];
        wsb[cell] = sum;                        // coalesced
    }
}

// Reduce: sum 16 slices' raw bins per graph, then prefix over c -> out[g][s][t]
__global__ __launch_bounds__(256) void ect_reduce(
    const float* __restrict__ ws, float* __restrict__ out)
{
    __shared__ float red[33 * 64];
    const int g   = blockIdx.x;
    const int tid = threadIdx.x;

    float a[9];
#pragma unroll
    for (int k = 0; k < 9; k++) a[k] = 0.0f;
#pragma unroll 1
    for (int i = 0; i < NSPLIT; i++) {
        const float* wsb = ws + (size_t)(g * NSPLIT + i) * (33 * 64);
#pragma unroll
        for (int k = 0; k < 9; k++) {
            const int cell = tid + 256 * k;
            if (cell < 33 * 64) a[k] += wsb[cell];   // coalesced
        }
    }
#pragma unroll
    for (int k = 0; k < 9; k++) {
        const int cell = tid + 256 * k;
        if (cell < 33 * 64) red[cell] = a[k];
    }
    __syncthreads();

    const int t = tid & 63;
    const int w = tid >> 6;
    float run = red[t];                          // base = profile value at s=0
    for (int cc = 1; cc < 8 * w; cc++) run += red[cc * 64 + t];
    float* og = out + g * (S * T);
#pragma unroll
    for (int j = 0; j < 8; j++) {
        const int s = 8 * w + j;
        if (s >= 1) run += red[s * 64 + t];
        og[s * 64 + t] = run;                    // plain store; covers zeroing
    }
}

extern "C" void kernel_launch(void* const* d_in, const int* in_sizes, int n_in,
                              void* d_out, int out_size, void* d_ws, size_t ws_size,
                              hipStream_t stream) {
    const float* x     = (const float*)d_in[0];
    const float* v     = (const float*)d_in[1];
    const float* lin   = (const float*)d_in[2];
    const int*   batch = (const int*)d_in[3];
    float* out = (float*)d_out;
    float* ws  = (float*)d_ws;                   // 1024 * 2112 floats = 8.65 MB

    const int n_points = in_sizes[0] / 3;

    ect_partial<<<NGRAPH * NSPLIT, 256, 0, stream>>>(x, v, lin, batch, ws, n_points);
    ect_reduce<<<NGRAPH, 256, 0, stream>>>(ws, out);
}

// Round 10
// 74.184 us; speedup vs baseline: 1.2698x; 1.2698x over previous
//
#include <hip/hip_runtime.h>

#define T      64
#define S      32
#define NGRAPH 64
#define NSPLIT 16     // slices per graph -> 1024 blocks of 256 (4 blocks/CU)
#define NW     4

// Delta-encoded ECT, 3-delta / 2-rcp version (R9 numerics, R8 structure).
// Per (node,theta) the sigmoid profile over s is 0..0, sm, s0, ~1..1; its
// first difference has 3 nonzero entries at slots ss-1, ss, ss+1 (third
// approximated as 1-s0v; true value differs by <= 8.2e-4). Slots <=0 fold
// into a base register (profile value at s=0); slots >=32 -> trash bin 33.
// LDS RMW as reads-then-writes (R8 pattern: pipelined, not serialized).
// Prefix-sum done in-partial; ws gets prefixed [32,64] per block.
__global__ __launch_bounds__(256, 4) void ect_partial(
    const float* __restrict__ x, const float* __restrict__ v,
    const float* __restrict__ lin, const int* __restrict__ batch,
    float* __restrict__ ws, int n_points)
{
    __shared__ float bins[256 * 34];  // [tid][c]: 0=base, 1..31 deltas, 33 trash

    const int tid  = threadIdx.x;
    const int t    = tid & 63;        // lane == theta
    const int w    = tid >> 6;        // wave id
    const int b    = blockIdx.x;
    const int g    = b >> 4;          // graph
    const int c    = b & (NSPLIT - 1);

    // vectorized zero-init: 8704 floats = 2176 float4
    {
        const float4 z4 = {0.0f, 0.0f, 0.0f, 0.0f};
        float4* b4 = (float4*)bins;
        for (int i = tid; i < 256 * 34 / 4; i += 256) b4[i] = z4;
    }

    // 32-ary ballot search (lanes<32: lower_bound(g), >=32: lower_bound(g+1))
    const int target = (t < 32) ? g : (g + 1);
    const int i32    = t & 31;
    int lo = 0;
    const int strides[3] = {2048, 64, 2};
#pragma unroll
    for (int rnd = 0; rnd < 3; rnd++) {
        const int stride = strides[rnd];
        const int idx  = lo + i32 * stride;
        const int pv   = batch[min(idx, n_points - 1)];
        const bool prd = (idx < n_points) && (pv < target);
        const unsigned long long bal = __ballot(prd);
        const int cnt = __popc((unsigned)(bal >> (t & 32)));
        lo += max(cnt - 1, 0) * stride;
    }
#pragma unroll
    for (int rnd = 0; rnd < 2; rnd++) {         // final range of 2
        const int idx = min(lo, n_points - 1);
        if ((lo < n_points) && (batch[idx] < target)) lo++;
    }
    const int gstart = __builtin_amdgcn_readfirstlane(lo);
    const int gend   = __builtin_amdgcn_readlane(lo, 32);
    const int len    = gend - gstart;
    const int n0     = gstart + (len * c) / NSPLIT;
    const int n1     = gstart + (len * (c + 1)) / NSPLIT;

    const float lin0     = lin[0];
    const float step     = lin[1] - lin0;
    const float inv_step = 1.0f / step;
    const float nl0i     = -lin0 * inv_step;
    const float K2 = (100.0f * step) * 1.4426950408889634f;   // ~10.24
    const float r  = __builtin_amdgcn_exp2f(-K2);

    const float v0 = v[0 * T + t];
    const float v1 = v[1 * T + t];
    const float v2 = v[2 * T + t];

    float v0acc = 0.0f;                 // profile value at s=0
    const int binb = tid * 34;
    __syncthreads();                    // bins init visible (same-thread anyway)

#pragma unroll 2
    for (int n = n0 + w; n < n1; n += NW) {     // n wave-uniform
        const float x0 = x[3 * n + 0];
        const float x1 = x[3 * n + 1];
        const float x2 = x[3 * n + 2];
        const float nh = fmaf(x0, v0, fmaf(x1, v1, x2 * v2));
        const float f  = fmaf(nh, inv_step, nl0i);
        const float fs = ceilf(f);
        const int   ss = (int)fs;
        const float e0 = __builtin_amdgcn_exp2f(fmaf(K2, f - fs, K2)); // (1,e^d]
        const float e1 = e0 * r;                                        // (r,1]
        const float sm  = __builtin_amdgcn_rcpf(1.0f + e0);
        const float s0v = __builtin_amdgcn_rcpf(1.0f + e1);
        v0acc += (ss <= -1) ? 1.0f : (ss == 0 ? s0v : (ss == 1 ? sm : 0.0f));
        // deltas at slots ss-1, ss, ss+1; in-range [1,31] else trash (33)
        const int p0 = ss - 1, p1 = ss, p2 = ss + 1;
        const int a0 = binb + (((unsigned)(p0 - 1) < 31u) ? p0 : 33);
        const int a1 = binb + (((unsigned)(p1 - 1) < 31u) ? p1 : 33);
        const int a2 = binb + (((unsigned)(p2 - 1) < 31u) ? p2 : 33);
        // reads first, then writes (in-range addrs distinct; trash dontcare)
        const float r0 = bins[a0], r1 = bins[a1], r2 = bins[a2];
        bins[a0] = r0 + sm;
        bins[a1] = r1 + (s0v - sm);
        bins[a2] = r2 + (1.0f - s0v);
    }

    bins[binb + 0] = v0acc;
    __syncthreads();

    // merge 4 wave-banks into bank 0 (c = 0..31 needed; skip trash)
    for (int cell = tid; cell < 32 * 64; cell += 256) {
        const int cc = cell >> 6;               // 0..31
        const int tt = cell & 63;
        const float sum = bins[(  0 + tt) * 34 + cc] + bins[( 64 + tt) * 34 + cc]
                        + bins[(128 + tt) * 34 + cc] + bins[(192 + tt) * 34 + cc];
        bins[tt * 34 + cc] = sum;
    }
    __syncthreads();

    // prefix over c and coalesced store: wave w covers s in [8w, 8w+8)
    float run = bins[t * 34 + 0];               // base = value at s=0
    const int sbase = 8 * w;
    for (int cc = 1; cc < sbase; cc++) run += bins[t * 34 + cc];
    float* wsb = ws + (size_t)b * (S * T);
#pragma unroll
    for (int j = 0; j < 8; j++) {
        const int s = sbase + j;
        if (s >= 1) run += bins[t * 34 + s];
        wsb[s * T + t] = run;
    }
}

// Phase 2: out[g][i] = sum of 16 prefixed slice partials (covers zeroing)
__global__ __launch_bounds__(256) void ect_reduce(
    const float* __restrict__ ws, float* __restrict__ out)
{
    const int idx = blockIdx.x * 256 + threadIdx.x;
    const int g   = idx >> 11;
    const int i   = idx & 2047;
    float sum = 0.0f;
#pragma unroll
    for (int c = 0; c < NSPLIT; c++)
        sum += ws[(size_t)(g * NSPLIT + c) * (S * T) + i];
    out[idx] = sum;
}

extern "C" void kernel_launch(void* const* d_in, const int* in_sizes, int n_in,
                              void* d_out, int out_size, void* d_ws, size_t ws_size,
                              hipStream_t stream) {
    const float* x     = (const float*)d_in[0];
    const float* v     = (const float*)d_in[1];
    const float* lin   = (const float*)d_in[2];
    const int*   batch = (const int*)d_in[3];
    float* out = (float*)d_out;
    float* ws  = (float*)d_ws;                   // 1024 * 2048 floats = 8 MB

    const int n_points = in_sizes[0] / 3;

    ect_partial<<<NGRAPH * NSPLIT, 256, 0, stream>>>(x, v, lin, batch, ws, n_points);
    ect_reduce<<<NGRAPH * S * T / 256, 256, 0, stream>>>(ws, out);
}